// Round 10
// baseline (244.404 us; speedup 1.0000x reference)
//
#include <hip/hip_runtime.h>
#include <hip/hip_bf16.h>
#include <stdint.h>

#define DM   1024
#define DKV  64
#define HEADS 16
#define BATCH 2
#define SEQ  2048
#define BS   (BATCH*SEQ)    // 4096
#define BHD  (BATCH*HEADS)  // 32

typedef __attribute__((ext_vector_type(8))) short bf16x8;
typedef __attribute__((ext_vector_type(4))) short bf16x4;
typedef __attribute__((ext_vector_type(4))) float f32x4;

// ---------- helpers ----------
__device__ inline unsigned fb(float f) { union { float f; unsigned u; } v; v.f = f; return v.u; }

__device__ inline unsigned short bf16_rtn(float f) {
  unsigned u = fb(f);
  unsigned r = u + 0x7fffu + ((u >> 16) & 1u);
  return (unsigned short)(r >> 16);
}
__device__ inline float bf16_to_f(unsigned short h) {
  union { unsigned u; float f; } v; v.u = ((unsigned)h) << 16; return v.f;
}
// split x ≈ hi + lo, |lo| <= 2^-9 |x|, residual ~2^-18
__device__ inline void split_bf16(float x, unsigned short& hi, unsigned short& lo) {
  hi = bf16_rtn(x);
  lo = bf16_rtn(x - bf16_to_f(hi));
}
// pack two fp32 -> two bf16 (round-half-up) in one dword via v_perm_b32
__device__ inline unsigned pack2_bf16(float lo_elem, float hi_elem) {
  return __builtin_amdgcn_perm(fb(hi_elem) + 0x8000u, fb(lo_elem) + 0x8000u, 0x07060302u);
}

__device__ inline float fast_exp2(float x) {
#if __has_builtin(__builtin_amdgcn_exp2f)
  return __builtin_amdgcn_exp2f(x);
#else
  return exp2f(x);
#endif
}

__device__ inline f32x4 mfma16x16x16_bf16(bf16x4 a, bf16x4 b, f32x4 c) {
#if __has_builtin(__builtin_amdgcn_mfma_f32_16x16x16bf16_1k)
  return __builtin_amdgcn_mfma_f32_16x16x16bf16_1k(a, b, c, 0, 0, 0);
#else
  asm volatile("v_mfma_f32_16x16x16_bf16 %0, %1, %2, %0" : "+v"(c) : "v"(a), "v"(b));
  return c;
#endif
}

// stage 16B/lane: async direct-to-LDS (dest = wave-uniform base + lane*16)
__device__ inline void stage16(const unsigned short* g, unsigned short* lds_base, int lane) {
#if __has_builtin(__builtin_amdgcn_global_load_lds)
  __builtin_amdgcn_global_load_lds((__attribute__((address_space(1))) void*)(g),
                                   (__attribute__((address_space(3))) void*)(lds_base),
                                   16, 0, 0);
#else
  *(bf16x8*)(lds_base + lane * 8) = *(const bf16x8*)g;
#endif
}

// XOR-swizzled LDS index for a 64-col bf16 tile (8 chunks of 8 shorts per row)
__device__ inline int swz(int row, int chunk) {
  return row * 64 + (((chunk ^ (row & 7)) & 7) << 3);
}

// ---------- fused prep: blocks [0,2048) cvt_x_split, [2048,2816) pack_qkv_split,
// ---------- [2816,3072) pack_wo.
__global__ void prep(const float* __restrict__ x,
                     const float* __restrict__ Wq, const float* __restrict__ Wk,
                     const float* __restrict__ Wv, const float* __restrict__ Wo,
                     unsigned short* __restrict__ xh, unsigned short* __restrict__ xl,
                     unsigned short* __restrict__ Wh, unsigned short* __restrict__ Wl,
                     unsigned short* __restrict__ WoT) {
  __shared__ float tile[64][65];
  const int bid = blockIdx.x;
  const int t = threadIdx.x;

  if (bid < 2048) {
    // ---- cvt_x_split ----
    int i = (bid * 256 + t) * 8;
    bf16x8 oh, ol;
    #pragma unroll
    for (int j = 0; j < 8; ++j) {
      unsigned short hi, lo;
      split_bf16(x[i + j], hi, lo);
      oh[j] = (short)hi; ol[j] = (short)lo;
    }
    *(bf16x8*)(xh + i) = oh;
    *(bf16x8*)(xl + i) = ol;
    return;
  }
  if (bid < 2816) {
    // ---- pack_qkv_split: b2 = p*256 + h*16 + mt ----
    int b2 = bid - 2048;
    int p = b2 >> 8, h = (b2 >> 4) & 15, mt = b2 & 15;
    const float* W = (p == 0) ? Wq : (p == 1) ? Wk : Wv;
    const float* src = W + (size_t)h * (DM * DKV);
    int m0 = mt * 64;
    #pragma unroll
    for (int pass = 0; pass < 16; ++pass) {
      int row = pass * 4 + (t >> 6), col = t & 63;
      tile[row][col] = src[(size_t)(m0 + row) * DKV + col];
    }
    __syncthreads();
    int cbase = p * 1024 + h * 64;
    #pragma unroll
    for (int pass = 0; pass < 16; ++pass) {
      int krow = pass * 4 + (t >> 6), mcol = t & 63;
      unsigned short hi, lo;
      split_bf16(tile[mcol][krow], hi, lo);
      size_t idx = (size_t)(cbase + krow) * DM + m0 + mcol;
      Wh[idx] = hi; Wl[idx] = lo;
    }
    return;
  }
  {
    // ---- pack_wo: b3 = ib*16 + jb ----
    int b3 = bid - 2816;
    int ib = b3 >> 4, jb = b3 & 15;
    #pragma unroll
    for (int pass = 0; pass < 16; ++pass) {
      int row = pass * 4 + (t >> 6), col = t & 63;
      tile[row][col] = Wo[(size_t)(ib * 64 + row) * DM + jb * 64 + col];
    }
    __syncthreads();
    #pragma unroll
    for (int pass = 0; pass < 16; ++pass) {
      int a = pass * 4 + (t >> 6), b = t & 63;
      WoT[(size_t)(jb * 64 + a) * DM + ib * 64 + b] = bf16_rtn(tile[b][a]);
    }
  }
}

// ---------- fused gemm_qkv: blocks 0..511 do x@Wqk^T (split, 128x128), ----------
// ---------- blocks 512..1023 do x@Wv^T (64x128) -> Vt.                 ----------
__global__ __launch_bounds__(256, 2)
void gemm_qkv(const unsigned short* __restrict__ Ah, const unsigned short* __restrict__ Al,
              const unsigned short* __restrict__ Bh, const unsigned short* __restrict__ Bl,
              unsigned short* __restrict__ Qh, unsigned short* __restrict__ Ql,
              unsigned short* __restrict__ Kh, unsigned short* __restrict__ Kl,
              unsigned short* __restrict__ Vt) {
  __shared__ unsigned short smem[32768];   // 64 KB
  const int tid = threadIdx.x;
  const int w = tid >> 6, lane = tid & 63;
  const int quad = lane >> 4, l16 = lane & 15;
  const int wm = w >> 1, wn = w & 1;
  const int bid = blockIdx.x;
  const int r8 = lane >> 3, c8 = lane & 7;
  const int cs = c8 ^ r8;

  if (bid < 512) {
    // ---- QK half: tile 128x128, BK=64, split-precision (3 MFMA/frag) ----
    unsigned short* AsH = smem;            // 8192 shorts
    unsigned short* AsL = smem + 8192;
    unsigned short* BsH = smem + 16384;
    unsigned short* BsL = smem + 24576;
    const int bn = bid & 15, bm = bid >> 4;

    f32x4 acc[4][4];
    #pragma unroll
    for (int i = 0; i < 4; ++i)
      #pragma unroll
      for (int j = 0; j < 4; ++j) acc[i][j] = (f32x4){0.f, 0.f, 0.f, 0.f};

    const size_t offA = (size_t)(bm * 128 + w * 32 + r8) * DM + cs * 8;
    const size_t offB = (size_t)(bn * 128 + w * 32 + r8) * DM + cs * 8;

    for (int kk = 0; kk < DM / 64; ++kk) {
      #pragma unroll
      for (int ps = 0; ps < 4; ++ps) {
        stage16(Ah + offA + kk * 64 + ps * 8 * DM, AsH + (w * 32 + ps * 8) * 64, lane);
        stage16(Al + offA + kk * 64 + ps * 8 * DM, AsL + (w * 32 + ps * 8) * 64, lane);
        stage16(Bh + offB + kk * 64 + ps * 8 * DM, BsH + (w * 32 + ps * 8) * 64, lane);
        stage16(Bl + offB + kk * 64 + ps * 8 * DM, BsL + (w * 32 + ps * 8) * 64, lane);
      }
      asm volatile("s_waitcnt vmcnt(0)" ::: "memory");
      __syncthreads();
      #pragma unroll
      for (int ks = 0; ks < 2; ++ks) {
        bf16x8 afh[4], afl[4], bfh[4], bfl[4];
        #pragma unroll
        for (int mt = 0; mt < 4; ++mt) {
          int row = wm * 64 + mt * 16 + l16;
          int ad = row * 64 + ((((ks * 4 + quad) ^ (row & 7)) & 7) << 3);
          afh[mt] = *(const bf16x8*)(AsH + ad);
          afl[mt] = *(const bf16x8*)(AsL + ad);
        }
        #pragma unroll
        for (int nt = 0; nt < 4; ++nt) {
          int row = wn * 64 + nt * 16 + l16;
          int ad = row * 64 + ((((ks * 4 + quad) ^ (row & 7)) & 7) << 3);
          bfh[nt] = *(const bf16x8*)(BsH + ad);
          bfl[nt] = *(const bf16x8*)(BsL + ad);
        }
        #pragma unroll
        for (int mt = 0; mt < 4; ++mt)
          #pragma unroll
          for (int nt = 0; nt < 4; ++nt) {
            acc[mt][nt] = __builtin_amdgcn_mfma_f32_16x16x32_bf16(afh[mt], bfh[nt], acc[mt][nt], 0, 0, 0);
            acc[mt][nt] = __builtin_amdgcn_mfma_f32_16x16x32_bf16(afh[mt], bfl[nt], acc[mt][nt], 0, 0, 0);
            acc[mt][nt] = __builtin_amdgcn_mfma_f32_16x16x32_bf16(afl[mt], bfh[nt], acc[mt][nt], 0, 0, 0);
          }
      }
      __syncthreads();
    }

    const float SCL = 0.18033688011112042f;  // (1/sqrt(64)) * log2(e), folded into Q
    #pragma unroll
    for (int mt = 0; mt < 4; ++mt) {
      int m_g = bm * 128 + wm * 64 + mt * 16 + quad * 4;
      #pragma unroll
      for (int nt = 0; nt < 4; ++nt) {
        int n_g = bn * 128 + wn * 64 + nt * 16 + l16;
        int p = n_g >> 10, h = (n_g >> 6) & 15, k = n_g & 63;
        #pragma unroll
        for (int r = 0; r < 4; ++r) {
          int row = m_g + r;
          int b = row >> 11, s = row & 2047;
          int bh = b * HEADS + h;
          float v = acc[mt][nt][r];
          size_t idx = ((size_t)(bh * SEQ + s)) * DKV + k;
          unsigned short hi, lo;
          if (p == 0) {
            split_bf16(v * SCL, hi, lo);
            Qh[idx] = hi; Ql[idx] = lo;
          } else {
            split_bf16(v, hi, lo);
            Kh[idx] = hi; Kl[idx] = lo;
          }
        }
      }
    }
  } else {
    // ---- V half: plain bf16, tile 64x128 -> Vt transposed ----
    unsigned short* As = smem;             // 4096 shorts
    unsigned short* Bs = smem + 4096;      // 8192 shorts
    const int vid = bid - 512;
    const int bn = vid & 7, bm = vid >> 3;
    const unsigned short* Bt = Bh + (size_t)2048 * DM;   // V weight rows of WcatT (hi)

    f32x4 acc[2][4];
    #pragma unroll
    for (int i = 0; i < 2; ++i)
      #pragma unroll
      for (int j = 0; j < 4; ++j) acc[i][j] = (f32x4){0.f, 0.f, 0.f, 0.f};

    const size_t offA = (size_t)(bm * 64 + w * 16 + r8) * DM + cs * 8;
    const size_t offB = (size_t)(bn * 128 + w * 32 + r8) * DM + cs * 8;

    for (int kk = 0; kk < DM / 64; ++kk) {
      #pragma unroll
      for (int ps = 0; ps < 2; ++ps)
        stage16(Ah + offA + kk * 64 + ps * 8 * DM, As + (w * 16 + ps * 8) * 64, lane);
      #pragma unroll
      for (int ps = 0; ps < 4; ++ps)
        stage16(Bt + offB + kk * 64 + ps * 8 * DM, Bs + (w * 32 + ps * 8) * 64, lane);
      asm volatile("s_waitcnt vmcnt(0)" ::: "memory");
      __syncthreads();
      #pragma unroll
      for (int ks = 0; ks < 2; ++ks) {
        bf16x8 af[2], bfr[4];
        #pragma unroll
        for (int mt = 0; mt < 2; ++mt) {
          int row = wm * 32 + mt * 16 + l16;
          af[mt] = *(const bf16x8*)(As + row * 64 + ((((ks * 4 + quad) ^ (row & 7)) & 7) << 3));
        }
        #pragma unroll
        for (int nt = 0; nt < 4; ++nt) {
          int row = wn * 64 + nt * 16 + l16;
          bfr[nt] = *(const bf16x8*)(Bs + row * 64 + ((((ks * 4 + quad) ^ (row & 7)) & 7) << 3));
        }
        #pragma unroll
        for (int mt = 0; mt < 2; ++mt)
          #pragma unroll
          for (int nt = 0; nt < 4; ++nt)
            acc[mt][nt] = __builtin_amdgcn_mfma_f32_16x16x32_bf16(af[mt], bfr[nt], acc[mt][nt], 0, 0, 0);
      }
      __syncthreads();
    }

    #pragma unroll
    for (int mt = 0; mt < 2; ++mt) {
      int m_g = bm * 64 + wm * 32 + mt * 16 + quad * 4;
      #pragma unroll
      for (int nt = 0; nt < 4; ++nt) {
        int n_g = bn * 128 + wn * 64 + nt * 16 + l16;   // 0..1023 within V block
        int h = n_g >> 6, k = n_g & 63;
        #pragma unroll
        for (int r = 0; r < 4; ++r) {
          int row = m_g + r;
          int b = row >> 11, s = row & 2047;
          int bh = b * HEADS + h;
          Vt[((size_t)(bh * DKV + k)) * SEQ + s] = bf16_rtn(acc[mt][nt][r]);
        }
      }
    }
  }
}

// ---------- flash: T4 counted-vmcnt pipeline + defer-max softmax ----------
// 256 threads, 4 waves, 32 q-rows/wave (qt=2). K TRIPLE-buffered (hi/lo),
// V double-buffered: 64 KB LDS, 2 blocks/CU.
// Per iter t: issue V(t+1) THEN K(t+3) (into dead slot t%3); compute
// softmax(t) striped with QK(t+1) [reads K[(t+1)%3]], PV(t) [reads V[t&1]];
// then s_waitcnt vmcnt(4) — waits the 6 oldest (K(t+2)+V(t+1)), LEAVES
// K(t+3) in flight across a raw s_barrier. The old vmcnt(0)+__syncthreads
// drained the just-issued K each iteration, exposing DMA latency to ALL
// waves simultaneously (why r4's 2x occupancy was null).
__global__ __launch_bounds__(256, 2)
void flash(const unsigned short* __restrict__ Qh, const unsigned short* __restrict__ Ql,
           const unsigned short* __restrict__ Kh, const unsigned short* __restrict__ Kl,
           const unsigned short* __restrict__ Vt, unsigned short* __restrict__ ctx) {
  __shared__ unsigned short KtH[3][64 * 64], KtL[3][64 * 64], Vts[2][64 * 64];
  const int tid = threadIdx.x;
  const int w = tid >> 6, lane = tid & 63, quad = lane >> 4, l16 = lane & 15;
  const int bh = blockIdx.x;
  const int q0 = blockIdx.y * 128;
  const int NT = SEQ / 64;   // 32

  // Q B-frags (scaled by SCL already): [n=q][k=d], split hi/lo
  bf16x8 qfh[2][2], qfl[2][2];
  #pragma unroll
  for (int qt = 0; qt < 2; ++qt) {
    int qrow = q0 + w * 32 + qt * 16 + l16;
    size_t base = ((size_t)(bh * SEQ + qrow)) * DKV + quad * 8;
    qfh[qt][0] = *(const bf16x8*)(Qh + base);
    qfh[qt][1] = *(const bf16x8*)(Qh + base + 32);
    qfl[qt][0] = *(const bf16x8*)(Ql + base);
    qfl[qt][1] = *(const bf16x8*)(Ql + base + 32);
  }

  float m_run[2] = {-1e30f, -1e30f};
  float l_run[2] = {0.f, 0.f};          // PER-LANE partial sums
  f32x4 acc[2][4];
  #pragma unroll
  for (int qt = 0; qt < 2; ++qt)
    #pragma unroll
    for (int vt = 0; vt < 4; ++vt) acc[qt][vt] = (f32x4){0.f, 0.f, 0.f, 0.f};

  const int srow = w * 16 + (lane >> 3);
  const int csrc = (lane & 7) ^ (lane >> 3);
  const unsigned short* kh_src = Kh + ((size_t)(bh * SEQ) + srow) * DKV + csrc * 8;
  const unsigned short* kl_src = Kl + ((size_t)(bh * SEQ) + srow) * DKV + csrc * 8;
  const unsigned short* v_src  = Vt + ((size_t)(bh * DKV) + srow) * SEQ + csrc * 8;

  #define STAGE_K(buf, kt0)                                                     \
    do {                                                                        \
      unsigned short* dH = &KtH[buf][(w * 16) * 64];                            \
      unsigned short* dL = &KtL[buf][(w * 16) * 64];                            \
      stage16(kh_src + (size_t)(kt0) * 64 * DKV,           dH,       lane);     \
      stage16(kh_src + (size_t)(kt0) * 64 * DKV + 8 * DKV, dH + 512, lane);     \
      stage16(kl_src + (size_t)(kt0) * 64 * DKV,           dL,       lane);     \
      stage16(kl_src + (size_t)(kt0) * 64 * DKV + 8 * DKV, dL + 512, lane);     \
    } while (0)
  #define STAGE_V(buf, kt0)                                                     \
    do {                                                                        \
      unsigned short* dV = &Vts[buf][(w * 16) * 64];                            \
      stage16(v_src + (kt0) * 64,           dV,       lane);                    \
      stage16(v_src + (kt0) * 64 + 8 * SEQ, dV + 512, lane);                    \
    } while (0)

  #define QK_HALF(STV, KHP, KLP, MT0)                                           \
    _Pragma("unroll")                                                           \
    for (int mt = (MT0); mt < (MT0) + 2; ++mt) {                                \
      int rowA = mt * 16 + l16;                                                 \
      bf16x8 kah0 = *(const bf16x8*)((KHP) + swz(rowA, quad));                  \
      bf16x8 kah1 = *(const bf16x8*)((KHP) + swz(rowA, quad + 4));              \
      bf16x8 kal0 = *(const bf16x8*)((KLP) + swz(rowA, quad));                  \
      bf16x8 kal1 = *(const bf16x8*)((KLP) + swz(rowA, quad + 4));              \
      _Pragma("unroll")                                                         \
      for (int qt = 0; qt < 2; ++qt) {                                          \
        f32x4 c = (f32x4){0.f, 0.f, 0.f, 0.f};                                  \
        c = __builtin_amdgcn_mfma_f32_16x16x32_bf16(kah0, qfh[qt][0], c, 0, 0, 0); \
        c = __builtin_amdgcn_mfma_f32_16x16x32_bf16(kah1, qfh[qt][1], c, 0, 0, 0); \
        c = __builtin_amdgcn_mfma_f32_16x16x32_bf16(kah0, qfl[qt][0], c, 0, 0, 0); \
        c = __builtin_amdgcn_mfma_f32_16x16x32_bf16(kah1, qfl[qt][1], c, 0, 0, 0); \
        c = __builtin_amdgcn_mfma_f32_16x16x32_bf16(kal0, qfh[qt][0], c, 0, 0, 0); \
        c = __builtin_amdgcn_mfma_f32_16x16x32_bf16(kal1, qfh[qt][1], c, 0, 0, 0); \
        (STV)[mt][qt] = c;                                                      \
      }                                                                         \
    }

  // defer-max online softmax for one qt: cross-lane + rescale only on vote fail
  #define SM_QT(QT)                                                             \
    {                                                                           \
      float cm = -1e30f;                                                        \
      _Pragma("unroll")                                                         \
      for (int mt = 0; mt < 4; ++mt)                                            \
        _Pragma("unroll")                                                       \
        for (int r = 0; r < 4; ++r) cm = fmaxf(cm, st[mt][QT][r]);              \
      if (!__all(cm <= m_run[QT] + 8.0f)) {                                     \
        cm = fmaxf(cm, __shfl_xor(cm, 16));                                     \
        cm = fmaxf(cm, __shfl_xor(cm, 32));                                     \
        float mn = fmaxf(cm, m_run[QT]);                                        \
        float alpha = fast_exp2(m_run[QT] - mn);                                \
        m_run[QT] = mn;                                                         \
        l_run[QT] *= alpha;                                                     \
        _Pragma("unroll")                                                       \
        for (int vt = 0; vt < 4; ++vt) acc[QT][vt] = acc[QT][vt] * alpha;       \
      }                                                                         \
      float mn = m_run[QT];                                                     \
      float ssum = 0.f;                                                         \
      _Pragma("unroll")                                                         \
      for (int mt = 0; mt < 4; ++mt) {                                          \
        float p0 = fast_exp2(st[mt][QT][0] - mn);                               \
        float p1 = fast_exp2(st[mt][QT][1] - mn);                               \
        float p2 = fast_exp2(st[mt][QT][2] - mn);                               \
        float p3 = fast_exp2(st[mt][QT][3] - mn);                               \
        ssum += (p0 + p1) + (p2 + p3);                                          \
        union { bf16x4 v; unsigned u2[2]; } pk;                                 \
        pk.u2[0] = pack2_bf16(p0, p1);                                          \
        pk.u2[1] = pack2_bf16(p2, p3);                                          \
        pb[QT][mt] = pk.v;                                                      \
      }                                                                         \
      l_run[QT] += ssum;                                                        \
    }

  #define PV_ALL(VSP)                                                           \
    _Pragma("unroll")                                                           \
    for (int vt = 0; vt < 4; ++vt)                                              \
      _Pragma("unroll")                                                         \
      for (int mt = 0; mt < 4; ++mt) {                                          \
        int row = vt * 16 + l16;                                                \
        int addr = row * 64 + ((((mt * 2 + (quad >> 1)) ^ (row & 7)) & 7) << 3) + (quad & 1) * 4; \
        bf16x4 va = *(const bf16x4*)((VSP) + addr);                             \
        _Pragma("unroll")                                                       \
        for (int qt = 0; qt < 2; ++qt)                                          \
          acc[qt][vt] = mfma16x16x16_bf16(va, pb[qt][mt], acc[qt][vt]);         \
      }

  // prologue: issue K0, V0, K1, K2 (14 loads); vmcnt(4) completes the 10
  // oldest (K0,V0,K1), leaves K2 in flight.
  STAGE_K(0, 0);
  STAGE_V(0, 0);
  STAGE_K(1, 1);
  STAGE_K(2, 2);
  asm volatile("s_waitcnt vmcnt(4)" ::: "memory");
  __builtin_amdgcn_s_barrier();
  __builtin_amdgcn_sched_barrier(0);

  f32x4 st[4][2];
  __builtin_amdgcn_s_setprio(1);
  QK_HALF(st, KtH[0], KtL[0], 0);
  QK_HALF(st, KtH[0], KtL[0], 2);
  __builtin_amdgcn_s_setprio(0);
  // all waves must finish reading K slot 0 before iter 0 overwrites it (K3)
  __builtin_amdgcn_s_barrier();
  __builtin_amdgcn_sched_barrier(0);

  #pragma unroll 2
  for (int t = 0; t < NT - 1; ++t) {
    // issue order matters for the counted wait: V(t+1) BEFORE K(t+3)
    STAGE_V((t + 1) & 1, t + 1);
    if (t + 3 < NT) STAGE_K(t % 3, t + 3);   // slot t%3 = K[t]'s dead slot

    const int kslot = (t + 1) % 3;
    const unsigned short* kHn = KtH[kslot];
    const unsigned short* kLn = KtL[kslot];
    const unsigned short* vS  = Vts[t & 1];

    bf16x4 pb[2][4];
    f32x4 stn[4][2];
    SM_QT(0);
    __builtin_amdgcn_s_setprio(1);
    QK_HALF(stn, kHn, kLn, 0);
    __builtin_amdgcn_s_setprio(0);
    SM_QT(1);
    __builtin_amdgcn_s_setprio(1);
    QK_HALF(stn, kHn, kLn, 2);
    PV_ALL(vS);
    __builtin_amdgcn_s_setprio(0);

    #pragma unroll
    for (int mt = 0; mt < 4; ++mt)
      #pragma unroll
      for (int qt = 0; qt < 2; ++qt) st[mt][qt] = stn[mt][qt];

    // counted wait: completes K(t+2)+V(t+1) (the 6 oldest), leaves K(t+3)
    // in flight across the barrier. Tail iterations (no K issue) drain fully.
    if (t < NT - 3) {
      asm volatile("s_waitcnt vmcnt(4)" ::: "memory");
    } else {
      asm volatile("s_waitcnt vmcnt(0)" ::: "memory");
    }
    __builtin_amdgcn_s_barrier();
    __builtin_amdgcn_sched_barrier(0);
  }

  // tail: softmax + PV of the last tile (V[31] in slot 1, drained above)
  {
    bf16x4 pb[2][4];
    SM_QT(0);
    SM_QT(1);
    PV_ALL(Vts[(NT - 1) & 1]);
  }
  #undef STAGE_K
  #undef STAGE_V
  #undef QK_HALF
  #undef SM_QT
  #undef PV_ALL

  // epilogue: reduce per-lane l partials across quads, then store ctx
  int h = bh & 15, b = bh >> 4;
  #pragma unroll
  for (int qt = 0; qt < 2; ++qt) {
    float lt = l_run[qt];
    lt += __shfl_xor(lt, 16);
    lt += __shfl_xor(lt, 32);
    float inv = 1.0f / lt;
    int bs = b * SEQ + q0 + w * 32 + qt * 16 + l16;
    #pragma unroll
    for (int vt = 0; vt < 4; ++vt) {
      union { bf16x4 v; unsigned u2[2]; } pk;
      pk.u2[0] = pack2_bf16(acc[qt][vt][0] * inv, acc[qt][vt][1] * inv);
      pk.u2[1] = pack2_bf16(acc[qt][vt][2] * inv, acc[qt][vt][3] * inv);
      *(bf16x4*)(ctx + (size_t)bs * DM + h * 64 + vt * 16 + quad * 4) = pk.v;
    }
  }
}

// ---------- GEMM2: ctx @ WoT^T -> fp32 out ----------
__global__ __launch_bounds__(256, 2)
void gemm_out(const unsigned short* __restrict__ A, const unsigned short* __restrict__ Bt,
              float* __restrict__ out) {
  __shared__ unsigned short As[64 * 64];     // 8 KB
  __shared__ unsigned short Bs[128 * 64];    // 16 KB
  const int tid = threadIdx.x;
  const int w = tid >> 6, lane = tid & 63;
  const int quad = lane >> 4, l16 = lane & 15;
  const int wm = w >> 1, wn = w & 1;
  const int bn = blockIdx.x, bm = blockIdx.y;

  f32x4 acc[2][4];
  #pragma unroll
  for (int i = 0; i < 2; ++i)
    #pragma unroll
    for (int j = 0; j < 4; ++j) acc[i][j] = (f32x4){0.f, 0.f, 0.f, 0.f};

  const int r8 = lane >> 3, c8 = lane & 7;
  const int cs = c8 ^ r8;
  const size_t offA = (size_t)(bm * 64 + w * 16 + r8) * DM + cs * 8;
  const size_t offB = (size_t)(bn * 128 + w * 32 + r8) * DM + cs * 8;

  for (int kk = 0; kk < DM / 64; ++kk) {
    #pragma unroll
    for (int ps = 0; ps < 2; ++ps)
      stage16(A + offA + kk * 64 + ps * 8 * DM, As + (w * 16 + ps * 8) * 64, lane);
    #pragma unroll
    for (int ps = 0; ps < 4; ++ps)
      stage16(Bt + offB + kk * 64 + ps * 8 * DM, Bs + (w * 32 + ps * 8) * 64, lane);
    asm volatile("s_waitcnt vmcnt(0)" ::: "memory");
    __syncthreads();
    #pragma unroll
    for (int ks = 0; ks < 2; ++ks) {
      bf16x8 af[2], bfr[4];
      #pragma unroll
      for (int mt = 0; mt < 2; ++mt) {
        int row = wm * 32 + mt * 16 + l16;
        af[mt] = *(const bf16x8*)(As + row * 64 + ((((ks * 4 + quad) ^ (row & 7)) & 7) << 3));
      }
      #pragma unroll
      for (int nt = 0; nt < 4; ++nt) {
        int row = wn * 64 + nt * 16 + l16;
        bfr[nt] = *(const bf16x8*)(Bs + row * 64 + ((((ks * 4 + quad) ^ (row & 7)) & 7) << 3));
      }
      #pragma unroll
      for (int mt = 0; mt < 2; ++mt)
        #pragma unroll
        for (int nt = 0; nt < 4; ++nt)
          acc[mt][nt] = __builtin_amdgcn_mfma_f32_16x16x32_bf16(af[mt], bfr[nt], acc[mt][nt], 0, 0, 0);
    }
    __syncthreads();
  }

  #pragma unroll
  for (int mt = 0; mt < 2; ++mt) {
    int m_g = bm * 64 + wm * 32 + mt * 16 + quad * 4;
    #pragma unroll
    for (int nt = 0; nt < 4; ++nt) {
      int n_g = bn * 128 + wn * 64 + nt * 16 + l16;
      #pragma unroll
      for (int r = 0; r < 4; ++r)
        out[(size_t)(m_g + r) * DM + n_g] = acc[mt][nt][r];
    }
  }
}

// ---------- launch ----------
extern "C" void kernel_launch(void* const* d_in, const int* in_sizes, int n_in,
                              void* d_out, int out_size, void* d_ws, size_t ws_size,
                              hipStream_t stream) {
  const float* x  = (const float*)d_in[0];
  const float* Wk = (const float*)d_in[1];
  const float* Wq = (const float*)d_in[2];
  const float* Wv = (const float*)d_in[3];
  const float* Wo = (const float*)d_in[4];
  float* out = (float*)d_out;

  unsigned short* xh  = (unsigned short*)d_ws;                  // [4096][1024]
  unsigned short* xl  = xh  + (size_t)BS * DM;
  unsigned short* Wh  = xl  + (size_t)BS * DM;                  // [3072][1024]
  unsigned short* Wl  = Wh  + (size_t)3 * DM * DM;
  unsigned short* WoT = Wl  + (size_t)3 * DM * DM;              // [1024][1024]
  unsigned short* Qh  = WoT + (size_t)DM * DM;                  // [32][2048][64]
  unsigned short* Ql  = Qh  + (size_t)BHD * SEQ * DKV;
  unsigned short* Kh  = Ql  + (size_t)BHD * SEQ * DKV;
  unsigned short* Kl  = Kh  + (size_t)BHD * SEQ * DKV;
  unsigned short* Vtb = Kl  + (size_t)BHD * SEQ * DKV;          // [32][64][2048]
  unsigned short* ctx = Vtb + (size_t)BHD * SEQ * DKV;          // [4096][1024]

  prep<<<3072, 256, 0, stream>>>(x, Wq, Wk, Wv, Wo, xh, xl, Wh, Wl, WoT);
  gemm_qkv<<<1024, 256, 0, stream>>>(xh, xl, Wh, Wl, Qh, Ql, Kh, Kl, Vtb);
  flash<<<dim3(BHD, SEQ / 128), 256, 0, stream>>>(Qh, Ql, Kh, Kl, Vtb, ctx);
  gemm_out<<<dim3(8, 64), 256, 0, stream>>>(ctx, WoT, out);
}

// Round 11
// 237.331 us; speedup vs baseline: 1.0298x; 1.0298x over previous
//
#include <hip/hip_runtime.h>
#include <hip/hip_bf16.h>
#include <stdint.h>

#define DM   1024
#define DKV  64
#define HEADS 16
#define BATCH 2
#define SEQ  2048
#define BS   (BATCH*SEQ)    // 4096
#define BHD  (BATCH*HEADS)  // 32

typedef __attribute__((ext_vector_type(8))) short bf16x8;
typedef __attribute__((ext_vector_type(4))) short bf16x4;
typedef __attribute__((ext_vector_type(4))) float f32x4;

// ---------- helpers ----------
__device__ inline unsigned fb(float f) { union { float f; unsigned u; } v; v.f = f; return v.u; }

__device__ inline unsigned short bf16_rtn(float f) {
  unsigned u = fb(f);
  unsigned r = u + 0x7fffu + ((u >> 16) & 1u);
  return (unsigned short)(r >> 16);
}
__device__ inline float bf16_to_f(unsigned short h) {
  union { unsigned u; float f; } v; v.u = ((unsigned)h) << 16; return v.f;
}
// split x ≈ hi + lo, |lo| <= 2^-9 |x|, residual ~2^-18
__device__ inline void split_bf16(float x, unsigned short& hi, unsigned short& lo) {
  hi = bf16_rtn(x);
  lo = bf16_rtn(x - bf16_to_f(hi));
}
// pack two fp32 -> two bf16 (round-half-up) in one dword via v_perm_b32
__device__ inline unsigned pack2_bf16(float lo_elem, float hi_elem) {
  return __builtin_amdgcn_perm(fb(hi_elem) + 0x8000u, fb(lo_elem) + 0x8000u, 0x07060302u);
}

__device__ inline float fast_exp2(float x) {
#if __has_builtin(__builtin_amdgcn_exp2f)
  return __builtin_amdgcn_exp2f(x);
#else
  return exp2f(x);
#endif
}

__device__ inline f32x4 mfma16x16x16_bf16(bf16x4 a, bf16x4 b, f32x4 c) {
#if __has_builtin(__builtin_amdgcn_mfma_f32_16x16x16bf16_1k)
  return __builtin_amdgcn_mfma_f32_16x16x16bf16_1k(a, b, c, 0, 0, 0);
#else
  asm volatile("v_mfma_f32_16x16x16_bf16 %0, %1, %2, %0" : "+v"(c) : "v"(a), "v"(b));
  return c;
#endif
}

// stage 16B/lane: async direct-to-LDS (dest = wave-uniform base + lane*16)
__device__ inline void stage16(const unsigned short* g, unsigned short* lds_base, int lane) {
#if __has_builtin(__builtin_amdgcn_global_load_lds)
  __builtin_amdgcn_global_load_lds((__attribute__((address_space(1))) void*)(g),
                                   (__attribute__((address_space(3))) void*)(lds_base),
                                   16, 0, 0);
#else
  *(bf16x8*)(lds_base + lane * 8) = *(const bf16x8*)g;
#endif
}

// XOR-swizzled LDS index for a 64-col bf16 tile (8 chunks of 8 shorts per row)
__device__ inline int swz(int row, int chunk) {
  return row * 64 + (((chunk ^ (row & 7)) & 7) << 3);
}

// ---------- fused prep: blocks [0,2048) cvt_x_split, [2048,2816) pack_qkv_split,
// ---------- [2816,3072) pack_wo.
__global__ void prep(const float* __restrict__ x,
                     const float* __restrict__ Wq, const float* __restrict__ Wk,
                     const float* __restrict__ Wv, const float* __restrict__ Wo,
                     unsigned short* __restrict__ xh, unsigned short* __restrict__ xl,
                     unsigned short* __restrict__ Wh, unsigned short* __restrict__ Wl,
                     unsigned short* __restrict__ WoT) {
  __shared__ float tile[64][65];
  const int bid = blockIdx.x;
  const int t = threadIdx.x;

  if (bid < 2048) {
    // ---- cvt_x_split ----
    int i = (bid * 256 + t) * 8;
    bf16x8 oh, ol;
    #pragma unroll
    for (int j = 0; j < 8; ++j) {
      unsigned short hi, lo;
      split_bf16(x[i + j], hi, lo);
      oh[j] = (short)hi; ol[j] = (short)lo;
    }
    *(bf16x8*)(xh + i) = oh;
    *(bf16x8*)(xl + i) = ol;
    return;
  }
  if (bid < 2816) {
    // ---- pack_qkv_split: b2 = p*256 + h*16 + mt ----
    int b2 = bid - 2048;
    int p = b2 >> 8, h = (b2 >> 4) & 15, mt = b2 & 15;
    const float* W = (p == 0) ? Wq : (p == 1) ? Wk : Wv;
    const float* src = W + (size_t)h * (DM * DKV);
    int m0 = mt * 64;
    #pragma unroll
    for (int pass = 0; pass < 16; ++pass) {
      int row = pass * 4 + (t >> 6), col = t & 63;
      tile[row][col] = src[(size_t)(m0 + row) * DKV + col];
    }
    __syncthreads();
    int cbase = p * 1024 + h * 64;
    #pragma unroll
    for (int pass = 0; pass < 16; ++pass) {
      int krow = pass * 4 + (t >> 6), mcol = t & 63;
      unsigned short hi, lo;
      split_bf16(tile[mcol][krow], hi, lo);
      size_t idx = (size_t)(cbase + krow) * DM + m0 + mcol;
      Wh[idx] = hi; Wl[idx] = lo;
    }
    return;
  }
  {
    // ---- pack_wo: b3 = ib*16 + jb ----
    int b3 = bid - 2816;
    int ib = b3 >> 4, jb = b3 & 15;
    #pragma unroll
    for (int pass = 0; pass < 16; ++pass) {
      int row = pass * 4 + (t >> 6), col = t & 63;
      tile[row][col] = Wo[(size_t)(ib * 64 + row) * DM + jb * 64 + col];
    }
    __syncthreads();
    #pragma unroll
    for (int pass = 0; pass < 16; ++pass) {
      int a = pass * 4 + (t >> 6), b = t & 63;
      WoT[(size_t)(jb * 64 + a) * DM + ib * 64 + b] = bf16_rtn(tile[b][a]);
    }
  }
}

// ---------- fused gemm_qkv: blocks 0..511 x@Wqk^T (split, 128x128), ----------
// ---------- blocks 512..1023 x@Wv^T (64x128) -> Vt.                  ----------
// BK=32: 32 KB LDS (was 64 KB at BK=64). m132 measured that 64 KB caps this
// structure at 2 blocks/CU -> ~510 TF; 32 KB restores 4 blocks/CU and the
// implicit dual-block overlap (m97/m114) that gives ~874 TF. Swizzle adapts
// to 4 chunks/row: src chunk = c4 ^ (row&3), read chunk = quad ^ (row&3).
__global__ __launch_bounds__(256, 4)
void gemm_qkv(const unsigned short* __restrict__ Ah, const unsigned short* __restrict__ Al,
              const unsigned short* __restrict__ Bh, const unsigned short* __restrict__ Bl,
              unsigned short* __restrict__ Qh, unsigned short* __restrict__ Ql,
              unsigned short* __restrict__ Kh, unsigned short* __restrict__ Kl,
              unsigned short* __restrict__ Vt) {
  __shared__ unsigned short smem[16384];   // 32 KB
  const int tid = threadIdx.x;
  const int w = tid >> 6, lane = tid & 63;
  const int quad = lane >> 4, l16 = lane & 15;
  const int wm = w >> 1, wn = w & 1;
  const int bid = blockIdx.x;
  // BK=32 staging geometry: 4 lanes/row (64 B), 16 rows per stage16
  const int r4s = lane >> 2, c4s = lane & 3;
  const int csY = c4s ^ (r4s & 3);         // involution of read-side swizzle

  if (bid < 512) {
    // ---- QK half: tile 128x128, BK=32, split-precision (3 MFMA/frag) ----
    unsigned short* AsH = smem;            // 4096 shorts (8 KB)
    unsigned short* AsL = smem + 4096;
    unsigned short* BsH = smem + 8192;
    unsigned short* BsL = smem + 12288;
    const int bn = bid & 15, bm = bid >> 4;

    f32x4 acc[4][4];
    #pragma unroll
    for (int i = 0; i < 4; ++i)
      #pragma unroll
      for (int j = 0; j < 4; ++j) acc[i][j] = (f32x4){0.f, 0.f, 0.f, 0.f};

    const size_t offA = (size_t)(bm * 128 + w * 32 + r4s) * DM + csY * 8;
    const size_t offB = (size_t)(bn * 128 + w * 32 + r4s) * DM + csY * 8;

    for (int kk = 0; kk < DM / 32; ++kk) {
      stage16(Ah + offA + kk * 32,           AsH + (w * 32) * 32,      lane);
      stage16(Ah + offA + kk * 32 + 16 * DM, AsH + (w * 32 + 16) * 32, lane);
      stage16(Al + offA + kk * 32,           AsL + (w * 32) * 32,      lane);
      stage16(Al + offA + kk * 32 + 16 * DM, AsL + (w * 32 + 16) * 32, lane);
      stage16(Bh + offB + kk * 32,           BsH + (w * 32) * 32,      lane);
      stage16(Bh + offB + kk * 32 + 16 * DM, BsH + (w * 32 + 16) * 32, lane);
      stage16(Bl + offB + kk * 32,           BsL + (w * 32) * 32,      lane);
      stage16(Bl + offB + kk * 32 + 16 * DM, BsL + (w * 32 + 16) * 32, lane);
      asm volatile("s_waitcnt vmcnt(0)" ::: "memory");
      __syncthreads();
      bf16x8 afh[4], afl[4], bfh[4], bfl[4];
      #pragma unroll
      for (int mt = 0; mt < 4; ++mt) {
        int row = wm * 64 + mt * 16 + l16;
        int ad = row * 32 + (((quad ^ (row & 3)) & 3) << 3);
        afh[mt] = *(const bf16x8*)(AsH + ad);
        afl[mt] = *(const bf16x8*)(AsL + ad);
      }
      #pragma unroll
      for (int nt = 0; nt < 4; ++nt) {
        int row = wn * 64 + nt * 16 + l16;
        int ad = row * 32 + (((quad ^ (row & 3)) & 3) << 3);
        bfh[nt] = *(const bf16x8*)(BsH + ad);
        bfl[nt] = *(const bf16x8*)(BsL + ad);
      }
      #pragma unroll
      for (int mt = 0; mt < 4; ++mt)
        #pragma unroll
        for (int nt = 0; nt < 4; ++nt) {
          acc[mt][nt] = __builtin_amdgcn_mfma_f32_16x16x32_bf16(afh[mt], bfh[nt], acc[mt][nt], 0, 0, 0);
          acc[mt][nt] = __builtin_amdgcn_mfma_f32_16x16x32_bf16(afh[mt], bfl[nt], acc[mt][nt], 0, 0, 0);
          acc[mt][nt] = __builtin_amdgcn_mfma_f32_16x16x32_bf16(afl[mt], bfh[nt], acc[mt][nt], 0, 0, 0);
        }
      __syncthreads();
    }

    const float SCL = 0.18033688011112042f;  // (1/sqrt(64)) * log2(e), folded into Q
    #pragma unroll
    for (int mt = 0; mt < 4; ++mt) {
      int m_g = bm * 128 + wm * 64 + mt * 16 + quad * 4;
      #pragma unroll
      for (int nt = 0; nt < 4; ++nt) {
        int n_g = bn * 128 + wn * 64 + nt * 16 + l16;
        int p = n_g >> 10, h = (n_g >> 6) & 15, k = n_g & 63;
        #pragma unroll
        for (int r = 0; r < 4; ++r) {
          int row = m_g + r;
          int b = row >> 11, s = row & 2047;
          int bh = b * HEADS + h;
          float v = acc[mt][nt][r];
          size_t idx = ((size_t)(bh * SEQ + s)) * DKV + k;
          unsigned short hi, lo;
          if (p == 0) {
            split_bf16(v * SCL, hi, lo);
            Qh[idx] = hi; Ql[idx] = lo;
          } else {
            split_bf16(v, hi, lo);
            Kh[idx] = hi; Kl[idx] = lo;
          }
        }
      }
    }
  } else {
    // ---- V half: plain bf16, tile 64x128, BK=32 -> Vt transposed ----
    unsigned short* As = smem;             // 2048 shorts (4 KB)
    unsigned short* Bs = smem + 2048;      // 4096 shorts (8 KB)
    const int vid = bid - 512;
    const int bn = vid & 7, bm = vid >> 3;
    const unsigned short* Bt = Bh + (size_t)2048 * DM;   // V weight rows of WcatT (hi)

    f32x4 acc[2][4];
    #pragma unroll
    for (int i = 0; i < 2; ++i)
      #pragma unroll
      for (int j = 0; j < 4; ++j) acc[i][j] = (f32x4){0.f, 0.f, 0.f, 0.f};

    const size_t offA = (size_t)(bm * 64 + w * 16 + r4s) * DM + csY * 8;
    const size_t offB = (size_t)(bn * 128 + w * 32 + r4s) * DM + csY * 8;

    for (int kk = 0; kk < DM / 32; ++kk) {
      stage16(Ah + offA + kk * 32,           As + (w * 16) * 32,      lane);
      stage16(Bt + offB + kk * 32,           Bs + (w * 32) * 32,      lane);
      stage16(Bt + offB + kk * 32 + 16 * DM, Bs + (w * 32 + 16) * 32, lane);
      asm volatile("s_waitcnt vmcnt(0)" ::: "memory");
      __syncthreads();
      bf16x8 af[2], bfr[4];
      #pragma unroll
      for (int mt = 0; mt < 2; ++mt) {
        int row = wm * 32 + mt * 16 + l16;
        af[mt] = *(const bf16x8*)(As + row * 32 + (((quad ^ (row & 3)) & 3) << 3));
      }
      #pragma unroll
      for (int nt = 0; nt < 4; ++nt) {
        int row = wn * 64 + nt * 16 + l16;
        bfr[nt] = *(const bf16x8*)(Bs + row * 32 + (((quad ^ (row & 3)) & 3) << 3));
      }
      #pragma unroll
      for (int mt = 0; mt < 2; ++mt)
        #pragma unroll
        for (int nt = 0; nt < 4; ++nt)
          acc[mt][nt] = __builtin_amdgcn_mfma_f32_16x16x32_bf16(af[mt], bfr[nt], acc[mt][nt], 0, 0, 0);
      __syncthreads();
    }

    #pragma unroll
    for (int mt = 0; mt < 2; ++mt) {
      int m_g = bm * 64 + wm * 32 + mt * 16 + quad * 4;
      #pragma unroll
      for (int nt = 0; nt < 4; ++nt) {
        int n_g = bn * 128 + wn * 64 + nt * 16 + l16;   // 0..1023 within V block
        int h = n_g >> 6, k = n_g & 63;
        #pragma unroll
        for (int r = 0; r < 4; ++r) {
          int row = m_g + r;
          int b = row >> 11, s = row & 2047;
          int bh = b * HEADS + h;
          Vt[((size_t)(bh * DKV + k)) * SEQ + s] = bf16_rtn(acc[mt][nt][r]);
        }
      }
    }
  }
}

// ---------- flash: T4 counted-vmcnt pipeline + defer-max softmax (r10, best) ----------
__global__ __launch_bounds__(256, 2)
void flash(const unsigned short* __restrict__ Qh, const unsigned short* __restrict__ Ql,
           const unsigned short* __restrict__ Kh, const unsigned short* __restrict__ Kl,
           const unsigned short* __restrict__ Vt, unsigned short* __restrict__ ctx) {
  __shared__ unsigned short KtH[3][64 * 64], KtL[3][64 * 64], Vts[2][64 * 64];
  const int tid = threadIdx.x;
  const int w = tid >> 6, lane = tid & 63, quad = lane >> 4, l16 = lane & 15;
  const int bh = blockIdx.x;
  const int q0 = blockIdx.y * 128;
  const int NT = SEQ / 64;   // 32

  // Q B-frags (scaled by SCL already): [n=q][k=d], split hi/lo
  bf16x8 qfh[2][2], qfl[2][2];
  #pragma unroll
  for (int qt = 0; qt < 2; ++qt) {
    int qrow = q0 + w * 32 + qt * 16 + l16;
    size_t base = ((size_t)(bh * SEQ + qrow)) * DKV + quad * 8;
    qfh[qt][0] = *(const bf16x8*)(Qh + base);
    qfh[qt][1] = *(const bf16x8*)(Qh + base + 32);
    qfl[qt][0] = *(const bf16x8*)(Ql + base);
    qfl[qt][1] = *(const bf16x8*)(Ql + base + 32);
  }

  float m_run[2] = {-1e30f, -1e30f};
  float l_run[2] = {0.f, 0.f};          // PER-LANE partial sums
  f32x4 acc[2][4];
  #pragma unroll
  for (int qt = 0; qt < 2; ++qt)
    #pragma unroll
    for (int vt = 0; vt < 4; ++vt) acc[qt][vt] = (f32x4){0.f, 0.f, 0.f, 0.f};

  const int srow = w * 16 + (lane >> 3);
  const int csrc = (lane & 7) ^ (lane >> 3);
  const unsigned short* kh_src = Kh + ((size_t)(bh * SEQ) + srow) * DKV + csrc * 8;
  const unsigned short* kl_src = Kl + ((size_t)(bh * SEQ) + srow) * DKV + csrc * 8;
  const unsigned short* v_src  = Vt + ((size_t)(bh * DKV) + srow) * SEQ + csrc * 8;

  #define STAGE_K(buf, kt0)                                                     \
    do {                                                                        \
      unsigned short* dH = &KtH[buf][(w * 16) * 64];                            \
      unsigned short* dL = &KtL[buf][(w * 16) * 64];                            \
      stage16(kh_src + (size_t)(kt0) * 64 * DKV,           dH,       lane);     \
      stage16(kh_src + (size_t)(kt0) * 64 * DKV + 8 * DKV, dH + 512, lane);     \
      stage16(kl_src + (size_t)(kt0) * 64 * DKV,           dL,       lane);     \
      stage16(kl_src + (size_t)(kt0) * 64 * DKV + 8 * DKV, dL + 512, lane);     \
    } while (0)
  #define STAGE_V(buf, kt0)                                                     \
    do {                                                                        \
      unsigned short* dV = &Vts[buf][(w * 16) * 64];                            \
      stage16(v_src + (kt0) * 64,           dV,       lane);                    \
      stage16(v_src + (kt0) * 64 + 8 * SEQ, dV + 512, lane);                    \
    } while (0)

  #define QK_HALF(STV, KHP, KLP, MT0)                                           \
    _Pragma("unroll")                                                           \
    for (int mt = (MT0); mt < (MT0) + 2; ++mt) {                                \
      int rowA = mt * 16 + l16;                                                 \
      bf16x8 kah0 = *(const bf16x8*)((KHP) + swz(rowA, quad));                  \
      bf16x8 kah1 = *(const bf16x8*)((KHP) + swz(rowA, quad + 4));              \
      bf16x8 kal0 = *(const bf16x8*)((KLP) + swz(rowA, quad));                  \
      bf16x8 kal1 = *(const bf16x8*)((KLP) + swz(rowA, quad + 4));              \
      _Pragma("unroll")                                                         \
      for (int qt = 0; qt < 2; ++qt) {                                          \
        f32x4 c = (f32x4){0.f, 0.f, 0.f, 0.f};                                  \
        c = __builtin_amdgcn_mfma_f32_16x16x32_bf16(kah0, qfh[qt][0], c, 0, 0, 0); \
        c = __builtin_amdgcn_mfma_f32_16x16x32_bf16(kah1, qfh[qt][1], c, 0, 0, 0); \
        c = __builtin_amdgcn_mfma_f32_16x16x32_bf16(kah0, qfl[qt][0], c, 0, 0, 0); \
        c = __builtin_amdgcn_mfma_f32_16x16x32_bf16(kah1, qfl[qt][1], c, 0, 0, 0); \
        c = __builtin_amdgcn_mfma_f32_16x16x32_bf16(kal0, qfh[qt][0], c, 0, 0, 0); \
        c = __builtin_amdgcn_mfma_f32_16x16x32_bf16(kal1, qfh[qt][1], c, 0, 0, 0); \
        (STV)[mt][qt] = c;                                                      \
      }                                                                         \
    }

  // defer-max online softmax for one qt: cross-lane + rescale only on vote fail
  #define SM_QT(QT)                                                             \
    {                                                                           \
      float cm = -1e30f;                                                        \
      _Pragma("unroll")                                                         \
      for (int mt = 0; mt < 4; ++mt)                                            \
        _Pragma("unroll")                                                       \
        for (int r = 0; r < 4; ++r) cm = fmaxf(cm, st[mt][QT][r]);              \
      if (!__all(cm <= m_run[QT] + 8.0f)) {                                     \
        cm = fmaxf(cm, __shfl_xor(cm, 16));                                     \
        cm = fmaxf(cm, __shfl_xor(cm, 32));                                     \
        float mn = fmaxf(cm, m_run[QT]);                                        \
        float alpha = fast_exp2(m_run[QT] - mn);                                \
        m_run[QT] = mn;                                                         \
        l_run[QT] *= alpha;                                                     \
        _Pragma("unroll")                                                       \
        for (int vt = 0; vt < 4; ++vt) acc[QT][vt] = acc[QT][vt] * alpha;       \
      }                                                                         \
      float mn = m_run[QT];                                                     \
      float ssum = 0.f;                                                         \
      _Pragma("unroll")                                                         \
      for (int mt = 0; mt < 4; ++mt) {                                          \
        float p0 = fast_exp2(st[mt][QT][0] - mn);                               \
        float p1 = fast_exp2(st[mt][QT][1] - mn);                               \
        float p2 = fast_exp2(st[mt][QT][2] - mn);                               \
        float p3 = fast_exp2(st[mt][QT][3] - mn);                               \
        ssum += (p0 + p1) + (p2 + p3);                                          \
        union { bf16x4 v; unsigned u2[2]; } pk;                                 \
        pk.u2[0] = pack2_bf16(p0, p1);                                          \
        pk.u2[1] = pack2_bf16(p2, p3);                                          \
        pb[QT][mt] = pk.v;                                                      \
      }                                                                         \
      l_run[QT] += ssum;                                                        \
    }

  #define PV_ALL(VSP)                                                           \
    _Pragma("unroll")                                                           \
    for (int vt = 0; vt < 4; ++vt)                                              \
      _Pragma("unroll")                                                         \
      for (int mt = 0; mt < 4; ++mt) {                                          \
        int row = vt * 16 + l16;                                                \
        int addr = row * 64 + ((((mt * 2 + (quad >> 1)) ^ (row & 7)) & 7) << 3) + (quad & 1) * 4; \
        bf16x4 va = *(const bf16x4*)((VSP) + addr);                             \
        _Pragma("unroll")                                                       \
        for (int qt = 0; qt < 2; ++qt)                                          \
          acc[qt][vt] = mfma16x16x16_bf16(va, pb[qt][mt], acc[qt][vt]);         \
      }

  // prologue: issue K0, V0, K1, K2 (14 loads); vmcnt(4) completes the 10
  // oldest (K0,V0,K1), leaves K2 in flight.
  STAGE_K(0, 0);
  STAGE_V(0, 0);
  STAGE_K(1, 1);
  STAGE_K(2, 2);
  asm volatile("s_waitcnt vmcnt(4)" ::: "memory");
  __builtin_amdgcn_s_barrier();
  __builtin_amdgcn_sched_barrier(0);

  f32x4 st[4][2];
  __builtin_amdgcn_s_setprio(1);
  QK_HALF(st, KtH[0], KtL[0], 0);
  QK_HALF(st, KtH[0], KtL[0], 2);
  __builtin_amdgcn_s_setprio(0);
  // all waves must finish reading K slot 0 before iter 0 overwrites it (K3)
  __builtin_amdgcn_s_barrier();
  __builtin_amdgcn_sched_barrier(0);

  #pragma unroll 2
  for (int t = 0; t < NT - 1; ++t) {
    // issue order matters for the counted wait: V(t+1) BEFORE K(t+3)
    STAGE_V((t + 1) & 1, t + 1);
    if (t + 3 < NT) STAGE_K(t % 3, t + 3);   // slot t%3 = K[t]'s dead slot

    const int kslot = (t + 1) % 3;
    const unsigned short* kHn = KtH[kslot];
    const unsigned short* kLn = KtL[kslot];
    const unsigned short* vS  = Vts[t & 1];

    bf16x4 pb[2][4];
    f32x4 stn[4][2];
    SM_QT(0);
    __builtin_amdgcn_s_setprio(1);
    QK_HALF(stn, kHn, kLn, 0);
    __builtin_amdgcn_s_setprio(0);
    SM_QT(1);
    __builtin_amdgcn_s_setprio(1);
    QK_HALF(stn, kHn, kLn, 2);
    PV_ALL(vS);
    __builtin_amdgcn_s_setprio(0);

    #pragma unroll
    for (int mt = 0; mt < 4; ++mt)
      #pragma unroll
      for (int qt = 0; qt < 2; ++qt) st[mt][qt] = stn[mt][qt];

    // counted wait: completes K(t+2)+V(t+1) (the 6 oldest), leaves K(t+3)
    // in flight across the barrier. Tail iterations (no K issue) drain fully.
    if (t < NT - 3) {
      asm volatile("s_waitcnt vmcnt(4)" ::: "memory");
    } else {
      asm volatile("s_waitcnt vmcnt(0)" ::: "memory");
    }
    __builtin_amdgcn_s_barrier();
    __builtin_amdgcn_sched_barrier(0);
  }

  // tail: softmax + PV of the last tile (V[31] in slot 1, drained above)
  {
    bf16x4 pb[2][4];
    SM_QT(0);
    SM_QT(1);
    PV_ALL(Vts[(NT - 1) & 1]);
  }
  #undef STAGE_K
  #undef STAGE_V
  #undef QK_HALF
  #undef SM_QT
  #undef PV_ALL

  // epilogue: reduce per-lane l partials across quads, then store ctx
  int h = bh & 15, b = bh >> 4;
  #pragma unroll
  for (int qt = 0; qt < 2; ++qt) {
    float lt = l_run[qt];
    lt += __shfl_xor(lt, 16);
    lt += __shfl_xor(lt, 32);
    float inv = 1.0f / lt;
    int bs = b * SEQ + q0 + w * 32 + qt * 16 + l16;
    #pragma unroll
    for (int vt = 0; vt < 4; ++vt) {
      union { bf16x4 v; unsigned u2[2]; } pk;
      pk.u2[0] = pack2_bf16(acc[qt][vt][0] * inv, acc[qt][vt][1] * inv);
      pk.u2[1] = pack2_bf16(acc[qt][vt][2] * inv, acc[qt][vt][3] * inv);
      *(bf16x4*)(ctx + (size_t)bs * DM + h * 64 + vt * 16 + quad * 4) = pk.v;
    }
  }
}

// ---------- GEMM2: ctx @ WoT^T -> fp32 out ----------
__global__ __launch_bounds__(256, 2)
void gemm_out(const unsigned short* __restrict__ A, const unsigned short* __restrict__ Bt,
              float* __restrict__ out) {
  __shared__ unsigned short As[64 * 64];     // 8 KB
  __shared__ unsigned short Bs[128 * 64];    // 16 KB
  const int tid = threadIdx.x;
  const int w = tid >> 6, lane = tid & 63;
  const int quad = lane >> 4, l16 = lane & 15;
  const int wm = w >> 1, wn = w & 1;
  const int bn = blockIdx.x, bm = blockIdx.y;

  f32x4 acc[2][4];
  #pragma unroll
  for (int i = 0; i < 2; ++i)
    #pragma unroll
    for (int j = 0; j < 4; ++j) acc[i][j] = (f32x4){0.f, 0.f, 0.f, 0.f};

  const int r8 = lane >> 3, c8 = lane & 7;
  const int cs = c8 ^ r8;
  const size_t offA = (size_t)(bm * 64 + w * 16 + r8) * DM + cs * 8;
  const size_t offB = (size_t)(bn * 128 + w * 32 + r8) * DM + cs * 8;

  for (int kk = 0; kk < DM / 64; ++kk) {
    #pragma unroll
    for (int ps = 0; ps < 2; ++ps)
      stage16(A + offA + kk * 64 + ps * 8 * DM, As + (w * 16 + ps * 8) * 64, lane);
    #pragma unroll
    for (int ps = 0; ps < 4; ++ps)
      stage16(Bt + offB + kk * 64 + ps * 8 * DM, Bs + (w * 32 + ps * 8) * 64, lane);
    asm volatile("s_waitcnt vmcnt(0)" ::: "memory");
    __syncthreads();
    #pragma unroll
    for (int ks = 0; ks < 2; ++ks) {
      bf16x8 af[2], bfr[4];
      #pragma unroll
      for (int mt = 0; mt < 2; ++mt) {
        int row = wm * 32 + mt * 16 + l16;
        af[mt] = *(const bf16x8*)(As + row * 64 + ((((ks * 4 + quad) ^ (row & 7)) & 7) << 3));
      }
      #pragma unroll
      for (int nt = 0; nt < 4; ++nt) {
        int row = wn * 64 + nt * 16 + l16;
        bfr[nt] = *(const bf16x8*)(Bs + row * 64 + ((((ks * 4 + quad) ^ (row & 7)) & 7) << 3));
      }
      #pragma unroll
      for (int mt = 0; mt < 2; ++mt)
        #pragma unroll
        for (int nt = 0; nt < 4; ++nt)
          acc[mt][nt] = __builtin_amdgcn_mfma_f32_16x16x32_bf16(af[mt], bfr[nt], acc[mt][nt], 0, 0, 0);
    }
    __syncthreads();
  }

  #pragma unroll
  for (int mt = 0; mt < 2; ++mt) {
    int m_g = bm * 64 + wm * 32 + mt * 16 + quad * 4;
    #pragma unroll
    for (int nt = 0; nt < 4; ++nt) {
      int n_g = bn * 128 + wn * 64 + nt * 16 + l16;
      #pragma unroll
      for (int r = 0; r < 4; ++r)
        out[(size_t)(m_g + r) * DM + n_g] = acc[mt][nt][r];
    }
  }
}

// ---------- launch ----------
extern "C" void kernel_launch(void* const* d_in, const int* in_sizes, int n_in,
                              void* d_out, int out_size, void* d_ws, size_t ws_size,
                              hipStream_t stream) {
  const float* x  = (const float*)d_in[0];
  const float* Wk = (const float*)d_in[1];
  const float* Wq = (const float*)d_in[2];
  const float* Wv = (const float*)d_in[3];
  const float* Wo = (const float*)d_in[4];
  float* out = (float*)d_out;

  unsigned short* xh  = (unsigned short*)d_ws;                  // [4096][1024]
  unsigned short* xl  = xh  + (size_t)BS * DM;
  unsigned short* Wh  = xl  + (size_t)BS * DM;                  // [3072][1024]
  unsigned short* Wl  = Wh  + (size_t)3 * DM * DM;
  unsigned short* WoT = Wl  + (size_t)3 * DM * DM;              // [1024][1024]
  unsigned short* Qh  = WoT + (size_t)DM * DM;                  // [32][2048][64]
  unsigned short* Ql  = Qh  + (size_t)BHD * SEQ * DKV;
  unsigned short* Kh  = Ql  + (size_t)BHD * SEQ * DKV;
  unsigned short* Kl  = Kh  + (size_t)BHD * SEQ * DKV;
  unsigned short* Vtb = Kl  + (size_t)BHD * SEQ * DKV;          // [32][64][2048]
  unsigned short* ctx = Vtb + (size_t)BHD * SEQ * DKV;          // [4096][1024]

  prep<<<3072, 256, 0, stream>>>(x, Wq, Wk, Wv, Wo, xh, xl, Wh, Wl, WoT);
  gemm_qkv<<<1024, 256, 0, stream>>>(xh, xl, Wh, Wl, Qh, Ql, Kh, Kl, Vtb);
  flash<<<dim3(BHD, SEQ / 128), 256, 0, stream>>>(Qh, Ql, Kh, Kl, Vtb, ctx);
  gemm_out<<<dim3(8, 64), 256, 0, stream>>>(ctx, WoT, out);
}